// Round 1
// baseline (12.818 us; speedup 1.0000x reference)
//
#include <hip/hip_runtime.h>

// Cosine-similarity all-pairs: W = normalize(emb) @ normalize(emb)^T, diag = 0.
// emb is [1024][100] fp32. Output [1024][1024] fp32, row-major (h-major),
// which matches p = h*N + t from repeat_interleave/tile of arange.

constexpr int N = 1024;
constexpr int D = 100;
constexpr int D4 = D / 4;   // 25 float4 chunks per row
constexpr int TILE = 64;

__global__ __launch_bounds__(256) void cosine_tiles(const float* __restrict__ emb,
                                                    float* __restrict__ out) {
    // Raw tiles: 64 rows x 100 floats each (25.6 KB x 2 = 51.2 KB LDS)
    __shared__ float sh[TILE * D];   // h-rows  (block row  by)
    __shared__ float st[TILE * D];   // t-rows  (block col  bx)
    __shared__ float sinvh[TILE];
    __shared__ float sinvt[TILE];

    const int tid = threadIdx.x;
    const int bx = blockIdx.x, by = blockIdx.y;

    // ---- stage global -> LDS (coalesced float4) ----
    const float4* hsrc = (const float4*)(emb + (size_t)by * TILE * D);
    const float4* tsrc = (const float4*)(emb + (size_t)bx * TILE * D);
    float4* shv = (float4*)sh;
    float4* stv = (float4*)st;
    for (int i = tid; i < TILE * D4; i += 256) {
        shv[i] = hsrc[i];
        stv[i] = tsrc[i];
    }
    __syncthreads();

    // ---- per-row inverse norms (threads 0..127, one row each) ----
    if (tid < 2 * TILE) {
        const float* row = (tid < TILE) ? &sh[tid * D] : &st[(tid - TILE) * D];
        float ss = 0.0f;
        #pragma unroll
        for (int c = 0; c < D4; ++c) {
            float4 v = *(const float4*)&row[4 * c];
            ss += v.x * v.x + v.y * v.y + v.z * v.z + v.w * v.w;
        }
        const float inv = 1.0f / sqrtf(ss);   // norms ~10 for this data; eps clamp irrelevant
        if (tid < TILE) sinvh[tid] = inv;
        else            sinvt[tid - TILE] = inv;
    }
    __syncthreads();

    // ---- 4x4 micro-tile per thread; row = ty+16i, col = tx+16j ----
    // (this mapping keeps B-operand ds_read_b128 at <=2-way bank aliasing)
    const int tx = tid & 15, ty = tid >> 4;
    float acc[4][4] = {};
    for (int k = 0; k < D4; ++k) {
        float4 a[4], b[4];
        #pragma unroll
        for (int i = 0; i < 4; ++i) a[i] = *(const float4*)&sh[(ty + 16 * i) * D + 4 * k];
        #pragma unroll
        for (int j = 0; j < 4; ++j) b[j] = *(const float4*)&st[(tx + 16 * j) * D + 4 * k];
        #pragma unroll
        for (int i = 0; i < 4; ++i)
            #pragma unroll
            for (int j = 0; j < 4; ++j)
                acc[i][j] += a[i].x * b[j].x + a[i].y * b[j].y
                           + a[i].z * b[j].z + a[i].w * b[j].w;
    }

    // ---- epilogue: scale by inv norms, zero diagonal, store ----
    #pragma unroll
    for (int i = 0; i < 4; ++i) {
        const int r = by * TILE + ty + 16 * i;
        const float ih = sinvh[ty + 16 * i];
        #pragma unroll
        for (int j = 0; j < 4; ++j) {
            const int c = bx * TILE + tx + 16 * j;
            const float w = acc[i][j] * ih * sinvt[tx + 16 * j];
            out[(size_t)r * N + c] = (r == c) ? 0.0f : w;
        }
    }
}

extern "C" void kernel_launch(void* const* d_in, const int* in_sizes, int n_in,
                              void* d_out, int out_size, void* d_ws, size_t ws_size,
                              hipStream_t stream) {
    (void)in_sizes; (void)n_in; (void)d_ws; (void)ws_size; (void)out_size;
    const float* emb = (const float*)d_in[2];   // d_in[0]/d_in[1] are arange repeat/tile ids
    float* out = (float*)d_out;
    dim3 grid(N / TILE, N / TILE);   // 16 x 16
    cosine_tiles<<<grid, 256, 0, stream>>>(emb, out);
}